// Round 9
// baseline (429.096 us; speedup 1.0000x reference)
//
#include <hip/hip_runtime.h>

#define W_ 640
#define H_ 480
#define HW_ (W_ * H_)
#define VAR_SPLIT 8
#define MAXNB_T 124         // bin fits 7 bits; accum4 LDS nb*256B <= 31.7KB
#define NBAND 120           // 4-px-high bands
#define NTX2 20             // 32-px-wide tiles per band
#define NT2 (NBAND * NTX2)  // 2400 tiles
#define TPX2 128            // 32x4 pixels per tile
#define FB 48               // pass1 LDS records per band bucket
#define FT 32               // pass1 flush threshold
#define FB2 256             // pass2 LDS records per tile bucket (20x256x4 = 20KB)
#define FT2 128             // pass2 flush threshold
#define PAD 16              // ints per cursor (64B line)
#define OVF 131072
#define EPT1 4              // events/thread/iter in pass1
#define CPB 8               // pass2 chunks per band

// ---- order-preserving float <-> uint key for atomic min ----
__device__ __forceinline__ unsigned fkey(float f) {
    unsigned u = __float_as_uint(f);
    return (u & 0x80000000u) ? ~u : (u | 0x80000000u);
}
__device__ __forceinline__ float finv(unsigned k) {
    unsigned u = (k & 0x80000000u) ? (k ^ 0x80000000u) : ~k;
    return __uint_as_float(u);
}
__device__ __forceinline__ float warp_t(float ts, float xf, float yf, float p0, float p1) {
    return __fsub_rn(__fsub_rn(ts, __fmul_rn(p0, xf)), __fmul_rn(p1, yf));
}

// exact-payload spill of a packed band record (band needed to rebuild coords)
__device__ __forceinline__ void spill_rec(unsigned r, int band,
                                          int* ovfcur, uint2* ovfrecs) {
    int j = atomicAdd(ovfcur, 1);
    if (j < OVF) {
        int pix = (int)((r >> 12) & 127u);
        int yi = band * 4 + (pix >> 5);
        int xi = (int)((r >> 19) & 31u) * 32 + (pix & 31);
        int b = (int)((r >> 24) & 127u);
        float wt = __fmul_rn((float)(r & 4095u), 2.44140625e-4f);
        unsigned px = ((unsigned)b << 20) | (unsigned)(yi * W_ + xi) | (r & 0x80000000u);
        ovfrecs[j] = make_uint2(px, __float_as_uint(wt));
    }
}

// K0: init. out zeroing only on slow path (fast paths overwrite every cell).
__global__ void k_init(float* __restrict__ out, int n4, unsigned* __restrict__ minbits,
                       int* __restrict__ ovfcur, double* __restrict__ sums, int nsums,
                       int* __restrict__ curs, int ncur) {
    int tid = blockIdx.x * blockDim.x + threadIdx.x;
    int stride = gridDim.x * blockDim.x;
    float4* o4 = (float4*)out;
    float4 z = make_float4(0.f, 0.f, 0.f, 0.f);
    for (int i = tid; i < n4; i += stride) o4[i] = z;
    for (int i = tid; i < ncur; i += stride) curs[i] = 0;
    if (tid == 0) { *minbits = 0xFFFFFFFFu; *ovfcur = 0; }
    if (tid < nsums) sums[tid] = 0.0;
}

// K1: global min of t_warped (proven)
__global__ void k_min(const float* __restrict__ x, const float* __restrict__ y,
                      const float* __restrict__ ts, const float* __restrict__ params,
                      int n, unsigned* __restrict__ minbits) {
    float p0 = params[0], p1 = params[1];
    int tid = blockIdx.x * blockDim.x + threadIdx.x;
    int stride = gridDim.x * blockDim.x;
    unsigned k = 0xFFFFFFFFu;
    for (int i = tid; i < n; i += stride) {
        unsigned kk = fkey(warp_t(ts[i], x[i], y[i], p0, p1));
        k = (kk < k) ? kk : k;
    }
    #pragma unroll
    for (int off = 32; off > 0; off >>= 1) {
        unsigned o = __shfl_down(k, off, 64);
        k = (o < k) ? o : k;
    }
    if ((threadIdx.x & 63) == 0) atomicMin(minbits, k);
}

// K2: LDS-staged band bucketing (proven).
// Record: [31]sign [30:24]bin [23:19]tilex [18:12]pix [11:0]wq.
__global__ void __launch_bounds__(256) k_pass1(
        const float* __restrict__ x, const float* __restrict__ y,
        const float* __restrict__ ts, const float* __restrict__ pol,
        const float* __restrict__ params, const float* __restrict__ bwp,
        int n, int nb, int cap1, int per, const unsigned* __restrict__ minbits,
        int* __restrict__ gcur, unsigned* __restrict__ recs1,
        int* __restrict__ ovfcur, uint2* __restrict__ ovfrecs) {
    __shared__ unsigned buf[NBAND][FB];
    __shared__ int cnt[NBAND];
    float p0 = params[0], p1 = params[1], bw = bwp[0];
    float tstart = finv(*minbits);
    float nbm1 = (float)(nb - 1);
    for (int t = threadIdx.x; t < NBAND; t += 256) cnt[t] = 0;
    __syncthreads();
    int lo = blockIdx.x * per;
    int hi = min(n, lo + per);
    int iters = (hi > lo) ? ((hi - lo + (EPT1 * 256 - 1)) / (EPT1 * 256)) : 0;
    int wave = threadIdx.x >> 6, lane = threadIdx.x & 63;
    for (int it = 0; it < iters; it++) {
        int ib = lo + it * (EPT1 * 256);
        float xf[EPT1], yf[EPT1], tf[EPT1], pf[EPT1];
        bool v[EPT1];
        #pragma unroll
        for (int k = 0; k < EPT1; k++) {
            int i = ib + (k << 8) + threadIdx.x;
            v[k] = (i < hi);
            if (v[k]) { xf[k] = x[i]; yf[k] = y[i]; tf[k] = ts[i]; pf[k] = pol[i]; }
        }
        #pragma unroll
        for (int k = 0; k < EPT1; k++) {
            if (v[k]) {
                int xi = (int)xf[k], yi = (int)yf[k];
                if (xi >= 0 && xi < W_ && yi >= 0 && yi < H_) {
                    float tn = __fdiv_rn(__fsub_rn(warp_t(tf[k], xf[k], yf[k], p0, p1), tstart), bw);
                    float t0f = floorf(tn);
                    float wt = __fsub_rn(tn, t0f);
                    int b = (int)fminf(fmaxf(t0f, 0.0f), nbm1);
                    unsigned sgn = __float_as_uint(pf[k]) & 0x80000000u;
                    int band = yi >> 2;
                    unsigned tilex = (unsigned)(xi >> 5);
                    unsigned pix = (unsigned)(((yi & 3) << 5) | (xi & 31));
                    unsigned wq = (unsigned)__fmul_rn(wt, 4096.0f);  // <= 4095
                    unsigned rec = sgn | ((unsigned)b << 24) | (tilex << 19) | (pix << 12) | wq;
                    int pos = atomicAdd(&cnt[band], 1);
                    if (pos < FB) buf[band][pos] = rec;
                    else {
                        int j = atomicAdd(ovfcur, 1);
                        if (j < OVF) {
                            unsigned px = ((unsigned)b << 20) | (unsigned)(yi * W_ + xi) | sgn;
                            ovfrecs[j] = make_uint2(px, __float_as_uint(wt));
                        }
                    }
                }
            }
        }
        __syncthreads();
        bool last = (it == iters - 1);
        for (int bb = wave; bb < NBAND; bb += 4) {
            int c = min(cnt[bb], FB);
            if (c >= (last ? 1 : FT)) {
                int base = 0;
                if (lane == 0) base = atomicAdd(&gcur[bb * PAD], c);
                base = __shfl(base, 0, 64);
                for (int j = lane; j < c; j += 64) {
                    unsigned r = buf[bb][j];
                    int idx = base + j;
                    if (idx < cap1) recs1[(size_t)bb * cap1 + idx] = r;
                    else spill_rec(r, bb, ovfcur, ovfrecs);
                }
                if (lane == 0) cnt[bb] = 0;
            }
        }
        __syncthreads();
    }
}

// K3: sub-bucket each band segment into exact per-tile segments (proven).
__global__ void __launch_bounds__(256) k_pass2(
        const unsigned* __restrict__ recs1, const int* __restrict__ gcur,
        int cap1, int cap2, int* __restrict__ tcur, unsigned* __restrict__ recs2,
        int* __restrict__ ovfcur, uint2* __restrict__ ovfrecs) {
    __shared__ unsigned buf[NTX2][FB2];
    __shared__ int cnt[NTX2];
    int band = blockIdx.x / CPB;
    int chunk = blockIdx.x % CPB;
    int c1 = min(gcur[band * PAD], cap1);
    int chunklen = (((c1 + CPB - 1) / CPB) + 3) & ~3;
    int start = chunk * chunklen;
    int end = min(start + chunklen, c1);
    const unsigned* seg = recs1 + (size_t)band * cap1;
    for (int t = threadIdx.x; t < NTX2; t += 256) cnt[t] = 0;
    __syncthreads();
    int iters = (end > start) ? ((end - start + 1023) >> 10) : 0;
    int wave = threadIdx.x >> 6, lane = threadIdx.x & 63;
    for (int it = 0; it < iters; it++) {
        int idx = start + (it << 10) + (int)threadIdx.x * 4;
        unsigned r4[4];
        int m = 0;
        if (idx + 4 <= end) {
            uint4 q = *(const uint4*)&seg[idx];
            r4[0] = q.x; r4[1] = q.y; r4[2] = q.z; r4[3] = q.w; m = 4;
        } else {
            for (; idx + m < end && m < 4; m++) r4[m] = seg[idx + m];
        }
        #pragma unroll
        for (int k = 0; k < 4; k++) {
            if (k < m) {
                unsigned r = r4[k];
                int tx = min((int)((r >> 19) & 31u), NTX2 - 1);  // defensive
                int pos = atomicAdd(&cnt[tx], 1);
                if (pos < FB2) buf[tx][pos] = r;
                else spill_rec(r, band, ovfcur, ovfrecs);
            }
        }
        __syncthreads();
        bool last = (it == iters - 1);
        for (int bb = wave; bb < NTX2; bb += 4) {
            int c = min(cnt[bb], FB2);
            if (c >= (last ? 1 : FT2)) {
                int base = 0;
                if (lane == 0) base = atomicAdd(&tcur[(band * NTX2 + bb) * PAD], c);
                base = __shfl(base, 0, 64);
                for (int j = lane; j < c; j += 64) {
                    unsigned r = buf[bb][j];
                    int o = base + j;
                    if (o < cap2) recs2[(size_t)(band * NTX2 + bb) * cap2 + o] = r;
                    else spill_rec(r, band, ovfcur, ovfrecs);
                }
                if (lane == 0) cnt[bb] = 0;
            }
        }
        __syncthreads();
    }
}

// K4 v2: one block per (tile, x-half). LDS = nb*64px*4B (~28KB) -> ~5 blocks/CU.
// float4 LDS clear, float4 stores. Scans full tile segment, filters bit pix[4].
__global__ void __launch_bounds__(256) k_accum4(
        const unsigned* __restrict__ recs2, const int* __restrict__ tcur,
        int nb, int cap2, float* __restrict__ out,
        double* __restrict__ sumv, double* __restrict__ sumsq) {
    extern __shared__ float acc[];  // nb * 64
    int T = blockIdx.x >> 1;
    unsigned hsel = blockIdx.x & 1;
    int ry = T / NTX2, tx = T % NTX2;
    int nacc4 = nb << 4;  // (nb*64)/4 float4s
    float4* acc4 = (float4*)acc;
    float4 z4 = make_float4(0.f, 0.f, 0.f, 0.f);
    for (int i = threadIdx.x; i < nacc4; i += 256) acc4[i] = z4;
    __syncthreads();
    int c2 = min(tcur[T * PAD], cap2);
    const unsigned* seg = recs2 + (size_t)T * cap2;
    int iters = (c2 + 1023) >> 10;
    for (int it = 0; it < iters; it++) {
        int idx = (it << 10) + (int)threadIdx.x * 4;
        unsigned r4[4];
        int m = 0;
        if (idx + 4 <= c2) {
            uint4 q = *(const uint4*)&seg[idx];
            r4[0] = q.x; r4[1] = q.y; r4[2] = q.z; r4[3] = q.w; m = 4;
        } else {
            for (; idx + m < c2 && m < 4; m++) r4[m] = seg[idx + m];
        }
        #pragma unroll
        for (int k = 0; k < 4; k++) {
            if (k < m) {
                unsigned r = r4[k];
                int pix = (int)((r >> 12) & 127u);
                if (((unsigned)(pix >> 4) & 1u) == hsel) {
                    int b = min((int)((r >> 24) & 127u), nb - 1);
                    int b1 = min(b + 1, nb - 1);
                    int l = ((pix >> 5) << 4) | (pix & 15);  // row*16 + col
                    unsigned sgn = r & 0x80000000u;
                    float wt = __fmul_rn((float)(r & 4095u), 2.44140625e-4f);  // /4096
                    float w0 = __uint_as_float(__float_as_uint(__fsub_rn(1.0f, wt)) ^ sgn);
                    float w1 = __uint_as_float(__float_as_uint(wt) ^ sgn);
                    atomicAdd(&acc[(b << 6) + l], w0);
                    atomicAdd(&acc[(b1 << 6) + l], w1);
                }
            }
        }
    }
    __syncthreads();
    int x0 = tx * 32 + (int)hsel * 16, y0 = ry * 4;
    // float4 store: i = b*16 + row*4 + qx  ->  out[b][y0+row][x0 + qx*4 .. +3]
    for (int i = threadIdx.x; i < nacc4; i += 256) {
        int b = i >> 4;
        int row = (i >> 2) & 3;
        int qx = i & 3;
        float4 v = acc4[i];
        *(float4*)&out[(size_t)b * HW_ + (size_t)(y0 + row) * W_ + x0 + (qx << 2)] = v;
    }
    // fused per-bin partial sums over this half-tile's 64 px (bank-staggered)
    if ((int)threadIdx.x < nb) {
        int b = threadIdx.x;
        double s = 0.0, ss = 0.0;
        for (int j2 = 0; j2 < 64; j2++) {
            float v = acc[(b << 6) + ((j2 + b) & 63)];
            double dv = (double)v;
            s += dv; ss += dv * dv;
        }
        atomicAdd(&sumv[b], s);
        atomicAdd(&sumsq[b], ss);
    }
}

// K4b (filter fallback, proven round 7): one block per tile, scans band segment.
__global__ void __launch_bounds__(256) k_accum2(
        const unsigned* __restrict__ recs1, const int* __restrict__ gcur,
        int nb, int cap1, float* __restrict__ out,
        double* __restrict__ sumv, double* __restrict__ sumsq) {
    extern __shared__ float acc[];
    int h = blockIdx.x;
    int xcd = h & 7;
    int j = h >> 3;
    int kk2 = j / NTX2;
    int tx = j % NTX2;
    int ry = xcd + 8 * kk2;
    int nacc = nb * TPX2;
    for (int i = threadIdx.x; i < nacc; i += 256) acc[i] = 0.f;
    __syncthreads();
    int c1 = min(gcur[ry * PAD], cap1);
    const unsigned* seg = recs1 + (size_t)ry * cap1;
    unsigned txu = (unsigned)tx;
    int iters = (c1 + 1023) >> 10;
    for (int it = 0; it < iters; it++) {
        int idx = (it << 10) + (int)threadIdx.x * 4;
        unsigned r4[4];
        int m = 0;
        if (idx + 4 <= c1) {
            uint4 q = *(const uint4*)&seg[idx];
            r4[0] = q.x; r4[1] = q.y; r4[2] = q.z; r4[3] = q.w; m = 4;
        } else {
            for (; idx + m < c1 && m < 4; m++) r4[m] = seg[idx + m];
        }
        #pragma unroll
        for (int k = 0; k < 4; k++) {
            if (k < m) {
                unsigned r = r4[k];
                if (((r >> 19) & 31u) == txu) {
                    int b = min((int)((r >> 24) & 127u), nb - 1);
                    int b1 = min(b + 1, nb - 1);
                    int pix = (int)((r >> 12) & 127u);
                    unsigned sgn = r & 0x80000000u;
                    float wt = __fmul_rn((float)(r & 4095u), 2.44140625e-4f);
                    float w0 = __uint_as_float(__float_as_uint(__fsub_rn(1.0f, wt)) ^ sgn);
                    float w1 = __uint_as_float(__float_as_uint(wt) ^ sgn);
                    atomicAdd(&acc[b * TPX2 + pix], w0);
                    atomicAdd(&acc[b1 * TPX2 + pix], w1);
                }
            }
        }
    }
    __syncthreads();
    int x0 = tx * 32, y0 = ry * 4;
    for (int i = threadIdx.x; i < nacc; i += 256) {
        int b = i >> 7, p = i & 127;
        int yy = y0 + (p >> 5), xx = x0 + (p & 31);
        out[(size_t)b * HW_ + yy * W_ + xx] = acc[i];
    }
    if ((int)threadIdx.x < nb) {
        int b = threadIdx.x;
        double s = 0.0, ss = 0.0;
        for (int j2 = 0; j2 < TPX2; j2++) {
            float v = acc[b * TPX2 + ((j2 + b) & 127)];
            double dv = (double)v;
            s += dv; ss += dv * dv;
        }
        atomicAdd(&sumv[b], s);
        atomicAdd(&sumsq[b], ss);
    }
}

// K5: replay overflow with direct atomics AFTER accumulation; compensates sums
// exactly via the old value returned by the atomic RMW.
__global__ void k_ovf(const uint2* __restrict__ ovfrecs, const int* __restrict__ ovfcur,
                      int nb, float* __restrict__ out,
                      double* __restrict__ sumv, double* __restrict__ sumsq) {
    int m = min(*ovfcur, OVF);
    int tid = blockIdx.x * blockDim.x + threadIdx.x;
    int stride = gridDim.x * blockDim.x;
    for (int i = tid; i < m; i += stride) {
        uint2 r = ovfrecs[i];
        unsigned sgn = r.x & 0x80000000u;
        int b = (int)((r.x >> 20) & 511u);
        int sp = (int)(r.x & 0x7FFFFu);
        b = min(b, nb - 1); sp = min(sp, HW_ - 1);
        int b1 = min(b + 1, nb - 1);
        float wt = __uint_as_float(r.y);
        float w0 = __uint_as_float(__float_as_uint(__fsub_rn(1.0f, wt)) ^ sgn);
        float w1 = __uint_as_float(r.y ^ sgn);
        float o0 = unsafeAtomicAdd(out + (size_t)b * HW_ + sp, w0);
        atomicAdd(&sumv[b], (double)w0);
        atomicAdd(&sumsq[b], (double)w0 * ((double)w0 + 2.0 * (double)o0));
        float o1 = unsafeAtomicAdd(out + (size_t)b1 * HW_ + sp, w1);
        atomicAdd(&sumv[b1], (double)w1);
        atomicAdd(&sumsq[b1], (double)w1 * ((double)w1 + 2.0 * (double)o1));
    }
}

// ---- slow fallback: round-1 unsorted scatter (proven, ~1000us) ----
__global__ void k_scatter(const float* __restrict__ x, const float* __restrict__ y,
                          const float* __restrict__ ts, const float* __restrict__ pol,
                          const float* __restrict__ params, const float* __restrict__ bwp,
                          int n, int nb, const unsigned* __restrict__ minbits,
                          float* __restrict__ out) {
    float p0 = params[0], p1 = params[1];
    float bw = bwp[0];
    float tstart = finv(*minbits);
    float nbm1 = (float)(nb - 1);
    int tid = blockIdx.x * blockDim.x + threadIdx.x;
    int stride = gridDim.x * blockDim.x;
    for (int i = tid; i < n; i += stride) {
        float xf = x[i], yf = y[i];
        float tn = __fdiv_rn(__fsub_rn(warp_t(ts[i], xf, yf, p0, p1), tstart), bw);
        float t0f = floorf(tn);
        float wt = __fsub_rn(tn, t0f);
        int t0c = (int)fminf(fmaxf(t0f, 0.0f), nbm1);
        int t1c = (int)fminf(fmaxf(__fadd_rn(t0f, 1.0f), 0.0f), nbm1);
        int xi = (int)xf, yi = (int)yf;
        if (xi >= 0 && xi < W_ && yi >= 0 && yi < H_) {
            int sp = yi * W_ + xi;
            float p = pol[i];
            float w0 = __fmul_rn(__fsub_rn(1.0f, wt), p);
            float w1 = __fmul_rn(wt, p);
            unsafeAtomicAdd(&out[(size_t)t0c * HW_ + sp], w0);
            unsafeAtomicAdd(&out[(size_t)t1c * HW_ + sp], w1);
        }
    }
}

// K6 (slow fallback only): per-bin sum/sumsq in double
__global__ void k_sums(const float* __restrict__ out, double* __restrict__ sumv,
                       double* __restrict__ sumsq) {
    int b = blockIdx.x / VAR_SPLIT;
    int part = blockIdx.x % VAR_SPLIT;
    const int chunk = HW_ / VAR_SPLIT;
    const float* p = out + (size_t)b * HW_ + (size_t)part * chunk;
    double s = 0.0, ss = 0.0;
    for (int i = threadIdx.x; i < chunk; i += blockDim.x) {
        double v = (double)p[i];
        s += v; ss += v * v;
    }
    #pragma unroll
    for (int off = 32; off > 0; off >>= 1) {
        s += __shfl_down(s, off, 64);
        ss += __shfl_down(ss, off, 64);
    }
    __shared__ double sb[8], sb2[8];
    int wave = threadIdx.x >> 6, lane = threadIdx.x & 63;
    if (lane == 0) { sb[wave] = s; sb2[wave] = ss; }
    __syncthreads();
    if (threadIdx.x == 0) {
        int nw = blockDim.x >> 6;
        for (int i = 1; i < nw; i++) { s += sb[i]; ss += sb2[i]; }
        atomicAdd(&sumv[b], s);
        atomicAdd(&sumsq[b], ss);
    }
}

// K7: variance per bin (ddof=1), mean -> loss
__global__ void k_final(const double* __restrict__ sumv, const double* __restrict__ sumsq,
                        int nb, float* __restrict__ loss) {
    double acc = 0.0;
    const double n = (double)HW_;
    for (int b = threadIdx.x; b < nb; b += blockDim.x) {
        double s = sumv[b], ss = sumsq[b];
        acc += (ss - s * s / n) / (n - 1.0);
    }
    #pragma unroll
    for (int off = 32; off > 0; off >>= 1) acc += __shfl_down(acc, off, 64);
    __shared__ double sb[8];
    int wave = threadIdx.x >> 6, lane = threadIdx.x & 63;
    if (lane == 0) sb[wave] = acc;
    __syncthreads();
    if (threadIdx.x == 0) {
        int nw = blockDim.x >> 6;
        for (int i = 1; i < nw; i++) acc += sb[i];
        *loss = (float)(acc / (double)nb);
    }
}

extern "C" void kernel_launch(void* const* d_in, const int* in_sizes, int n_in,
                              void* d_out, int out_size, void* d_ws, size_t ws_size,
                              hipStream_t stream) {
    const float* params = (const float*)d_in[0];
    const float* x      = (const float*)d_in[1];
    const float* y      = (const float*)d_in[2];
    const float* ts     = (const float*)d_in[3];
    const float* pol    = (const float*)d_in[4];
    const float* bwp    = (const float*)d_in[7];

    int n  = in_sizes[1];
    int nb = (out_size - 1) / HW_;
    float* out = (float*)d_out;

    // ws layout: minbits | ovfcur | sumv,sumsq | gcur[120*PAD] | tcur[2400*PAD]
    //            | ovfrecs[OVF] | recs1[120*cap1] | recs2[2400*cap2]
    size_t off_sums  = 128;
    size_t off_gcur  = (off_sums + 16ULL * nb + 63) & ~(size_t)63;
    size_t off_tcur  = off_gcur + 4ULL * NBAND * PAD;   // both 64B-multiples
    size_t off_ovfr  = (off_tcur + 4ULL * NT2 * PAD + 63) & ~(size_t)63;
    size_t off_recs1 = (off_ovfr + 8ULL * OVF + 63) & ~(size_t)63;

    unsigned* minbits = (unsigned*)d_ws;
    int*      ovfcur  = (int*)((char*)d_ws + 64);
    double*   sumv    = (double*)((char*)d_ws + off_sums);
    double*   sumsq   = sumv + nb;
    int*      gcur    = (int*)((char*)d_ws + off_gcur);
    int*      tcur    = (int*)((char*)d_ws + off_tcur);
    uint2*    ovfrecs = (uint2*)((char*)d_ws + off_ovfr);
    unsigned* recs1   = (unsigned*)((char*)d_ws + off_recs1);

    long long mean1 = (long long)n / NBAND;
    long long mean2 = (long long)n / NT2;

    // exact path: fixed cap1, adaptive cap2
    long long cap1e = (mean1 + mean1 / 8 + 2048) & ~3LL;
    size_t off_recs2 = (off_recs1 + 4ULL * NBAND * cap1e + 63) & ~(size_t)63;
    unsigned* recs2 = (unsigned*)((char*)d_ws + off_recs2);
    long long avail2 = (ws_size > off_recs2)
                       ? (long long)((ws_size - off_recs2) / (4ULL * NT2)) : 0;
    long long cap2min = mean2 + mean2 / 8 + 256;
    long long cap2max = 2 * mean2 + 1024;
    long long cap2ll = ((avail2 < cap2max) ? avail2 : cap2max) & ~3LL;
    bool exact = (n > 0) && (nb >= 1) && (nb <= MAXNB_T) && (cap2ll >= cap2min);

    // filter path (round-7): bigger cap1 allowed, no recs2
    long long avail1 = (ws_size > off_recs1)
                       ? (long long)((ws_size - off_recs1) / (4ULL * NBAND)) : 0;
    long long cap1f_max = 2 * mean1 + 4096;
    long long cap1fll = ((avail1 < cap1f_max) ? avail1 : cap1f_max) & ~3LL;
    bool filter = !exact && (n > 0) && (nb >= 1) && (nb <= MAXNB_T) &&
                  (cap1fll >= mean1 + mean1 / 12 + 2048);

    int cap1 = (int)(exact ? cap1e : cap1fll);
    int cap2 = (int)cap2ll;

    int n_tensor = nb * HW_;
    int n4 = (exact || filter) ? 0 : (n_tensor >> 2);

    const int BLK = 256;
    const int G1 = 1280;
    const int ITBLK = EPT1 * 256;
    int per = (((n + G1 - 1) / G1) + ITBLK - 1) / ITBLK * ITBLK;
    int g1used = (n + per - 1) / per;

    hipLaunchKernelGGL(k_init, dim3(2048), dim3(BLK), 0, stream,
                       out, n4, minbits, ovfcur, sumv, 2 * nb,
                       gcur, NBAND * PAD + NT2 * PAD);
    hipLaunchKernelGGL(k_min, dim3(2048), dim3(BLK), 0, stream,
                       x, y, ts, params, n, minbits);

    if (exact) {
        hipLaunchKernelGGL(k_pass1, dim3(g1used), dim3(BLK), 0, stream,
                           x, y, ts, pol, params, bwp, n, nb, cap1, per, minbits,
                           gcur, recs1, ovfcur, ovfrecs);
        hipLaunchKernelGGL(k_pass2, dim3(NBAND * CPB), dim3(BLK), 0, stream,
                           recs1, gcur, cap1, cap2, tcur, recs2, ovfcur, ovfrecs);
        hipLaunchKernelGGL(k_accum4, dim3(NT2 * 2), dim3(BLK), (size_t)nb * 64 * 4, stream,
                           recs2, tcur, nb, cap2, out, sumv, sumsq);
        hipLaunchKernelGGL(k_ovf, dim3(64), dim3(BLK), 0, stream,
                           ovfrecs, ovfcur, nb, out, sumv, sumsq);
    } else if (filter) {
        hipLaunchKernelGGL(k_pass1, dim3(g1used), dim3(BLK), 0, stream,
                           x, y, ts, pol, params, bwp, n, nb, cap1, per, minbits,
                           gcur, recs1, ovfcur, ovfrecs);
        hipLaunchKernelGGL(k_accum2, dim3(NT2), dim3(BLK), (size_t)nb * TPX2 * 4, stream,
                           recs1, gcur, nb, cap1, out, sumv, sumsq);
        hipLaunchKernelGGL(k_ovf, dim3(64), dim3(BLK), 0, stream,
                           ovfrecs, ovfcur, nb, out, sumv, sumsq);
    } else {
        hipLaunchKernelGGL(k_scatter, dim3(2048), dim3(BLK), 0, stream,
                           x, y, ts, pol, params, bwp, n, nb, minbits, out);
        hipLaunchKernelGGL(k_sums, dim3(nb * VAR_SPLIT), dim3(BLK), 0, stream,
                           out, sumv, sumsq);
    }

    hipLaunchKernelGGL(k_final, dim3(1), dim3(BLK), 0, stream,
                       sumv, sumsq, nb, out + n_tensor);
}

// Round 10
// 366.616 us; speedup vs baseline: 1.1704x; 1.1704x over previous
//
#include <hip/hip_runtime.h>

#define W_ 640
#define H_ 480
#define HW_ (W_ * H_)
#define VAR_SPLIT 8
#define MAXNB_T 124         // bin fits 7 bits; accum5 LDS nb*512B <= 63.5KB
#define NBAND 120           // 4-px-high bands
#define NTX2 20             // 32-px-wide tiles per band
#define NT2 (NBAND * NTX2)  // 2400 tiles
#define TPX2 128            // 32x4 pixels per tile
#define FB 48               // pass1 LDS records per band bucket
#define FT 32               // pass1 flush threshold
#define FB2 256             // pass2 LDS records per tile bucket (20x256x4 = 20KB)
#define FT2 128             // pass2 flush threshold
#define PAD 16              // ints per cursor (64B line)
#define OVF 131072
#define EPT1 4              // events/thread/iter in pass1
#define CPB 8               // pass2 chunks per band

// ---- order-preserving float <-> uint key for atomic min ----
__device__ __forceinline__ unsigned fkey(float f) {
    unsigned u = __float_as_uint(f);
    return (u & 0x80000000u) ? ~u : (u | 0x80000000u);
}
__device__ __forceinline__ float finv(unsigned k) {
    unsigned u = (k & 0x80000000u) ? (k ^ 0x80000000u) : ~k;
    return __uint_as_float(u);
}
__device__ __forceinline__ float warp_t(float ts, float xf, float yf, float p0, float p1) {
    return __fsub_rn(__fsub_rn(ts, __fmul_rn(p0, xf)), __fmul_rn(p1, yf));
}

// exact-payload spill of a packed band record (band needed to rebuild coords)
__device__ __forceinline__ void spill_rec(unsigned r, int band,
                                          int* ovfcur, uint2* ovfrecs) {
    int j = atomicAdd(ovfcur, 1);
    if (j < OVF) {
        int pix = (int)((r >> 12) & 127u);
        int yi = band * 4 + (pix >> 5);
        int xi = (int)((r >> 19) & 31u) * 32 + (pix & 31);
        int b = (int)((r >> 24) & 127u);
        float wt = __fmul_rn((float)(r & 4095u), 2.44140625e-4f);
        unsigned px = ((unsigned)b << 20) | (unsigned)(yi * W_ + xi) | (r & 0x80000000u);
        ovfrecs[j] = make_uint2(px, __float_as_uint(wt));
    }
}

// K0: init. out zeroing only on slow path (fast paths overwrite every cell).
__global__ void k_init(float* __restrict__ out, int n4, unsigned* __restrict__ minbits,
                       int* __restrict__ ovfcur, double* __restrict__ sums, int nsums,
                       int* __restrict__ curs, int ncur) {
    int tid = blockIdx.x * blockDim.x + threadIdx.x;
    int stride = gridDim.x * blockDim.x;
    float4* o4 = (float4*)out;
    float4 z = make_float4(0.f, 0.f, 0.f, 0.f);
    for (int i = tid; i < n4; i += stride) o4[i] = z;
    for (int i = tid; i < ncur; i += stride) curs[i] = 0;
    if (tid == 0) { *minbits = 0xFFFFFFFFu; *ovfcur = 0; }
    if (tid < nsums) sums[tid] = 0.0;
}

// K1: global min of t_warped (proven)
__global__ void k_min(const float* __restrict__ x, const float* __restrict__ y,
                      const float* __restrict__ ts, const float* __restrict__ params,
                      int n, unsigned* __restrict__ minbits) {
    float p0 = params[0], p1 = params[1];
    int tid = blockIdx.x * blockDim.x + threadIdx.x;
    int stride = gridDim.x * blockDim.x;
    unsigned k = 0xFFFFFFFFu;
    for (int i = tid; i < n; i += stride) {
        unsigned kk = fkey(warp_t(ts[i], x[i], y[i], p0, p1));
        k = (kk < k) ? kk : k;
    }
    #pragma unroll
    for (int off = 32; off > 0; off >>= 1) {
        unsigned o = __shfl_down(k, off, 64);
        k = (o < k) ? o : k;
    }
    if ((threadIdx.x & 63) == 0) atomicMin(minbits, k);
}

// K2: LDS-staged band bucketing (proven).
// Record: [31]sign [30:24]bin [23:19]tilex [18:12]pix [11:0]wq.
__global__ void __launch_bounds__(256) k_pass1(
        const float* __restrict__ x, const float* __restrict__ y,
        const float* __restrict__ ts, const float* __restrict__ pol,
        const float* __restrict__ params, const float* __restrict__ bwp,
        int n, int nb, int cap1, int per, const unsigned* __restrict__ minbits,
        int* __restrict__ gcur, unsigned* __restrict__ recs1,
        int* __restrict__ ovfcur, uint2* __restrict__ ovfrecs) {
    __shared__ unsigned buf[NBAND][FB];
    __shared__ int cnt[NBAND];
    float p0 = params[0], p1 = params[1], bw = bwp[0];
    float tstart = finv(*minbits);
    float nbm1 = (float)(nb - 1);
    for (int t = threadIdx.x; t < NBAND; t += 256) cnt[t] = 0;
    __syncthreads();
    int lo = blockIdx.x * per;
    int hi = min(n, lo + per);
    int iters = (hi > lo) ? ((hi - lo + (EPT1 * 256 - 1)) / (EPT1 * 256)) : 0;
    int wave = threadIdx.x >> 6, lane = threadIdx.x & 63;
    for (int it = 0; it < iters; it++) {
        int ib = lo + it * (EPT1 * 256);
        float xf[EPT1], yf[EPT1], tf[EPT1], pf[EPT1];
        bool v[EPT1];
        #pragma unroll
        for (int k = 0; k < EPT1; k++) {
            int i = ib + (k << 8) + threadIdx.x;
            v[k] = (i < hi);
            if (v[k]) { xf[k] = x[i]; yf[k] = y[i]; tf[k] = ts[i]; pf[k] = pol[i]; }
        }
        #pragma unroll
        for (int k = 0; k < EPT1; k++) {
            if (v[k]) {
                int xi = (int)xf[k], yi = (int)yf[k];
                if (xi >= 0 && xi < W_ && yi >= 0 && yi < H_) {
                    float tn = __fdiv_rn(__fsub_rn(warp_t(tf[k], xf[k], yf[k], p0, p1), tstart), bw);
                    float t0f = floorf(tn);
                    float wt = __fsub_rn(tn, t0f);
                    int b = (int)fminf(fmaxf(t0f, 0.0f), nbm1);
                    unsigned sgn = __float_as_uint(pf[k]) & 0x80000000u;
                    int band = yi >> 2;
                    unsigned tilex = (unsigned)(xi >> 5);
                    unsigned pix = (unsigned)(((yi & 3) << 5) | (xi & 31));
                    unsigned wq = (unsigned)__fmul_rn(wt, 4096.0f);  // <= 4095
                    unsigned rec = sgn | ((unsigned)b << 24) | (tilex << 19) | (pix << 12) | wq;
                    int pos = atomicAdd(&cnt[band], 1);
                    if (pos < FB) buf[band][pos] = rec;
                    else {
                        int j = atomicAdd(ovfcur, 1);
                        if (j < OVF) {
                            unsigned px = ((unsigned)b << 20) | (unsigned)(yi * W_ + xi) | sgn;
                            ovfrecs[j] = make_uint2(px, __float_as_uint(wt));
                        }
                    }
                }
            }
        }
        __syncthreads();
        bool last = (it == iters - 1);
        for (int bb = wave; bb < NBAND; bb += 4) {
            int c = min(cnt[bb], FB);
            if (c >= (last ? 1 : FT)) {
                int base = 0;
                if (lane == 0) base = atomicAdd(&gcur[bb * PAD], c);
                base = __shfl(base, 0, 64);
                for (int j = lane; j < c; j += 64) {
                    unsigned r = buf[bb][j];
                    int idx = base + j;
                    if (idx < cap1) recs1[(size_t)bb * cap1 + idx] = r;
                    else spill_rec(r, bb, ovfcur, ovfrecs);
                }
                if (lane == 0) cnt[bb] = 0;
            }
        }
        __syncthreads();
    }
}

// K3: sub-bucket each band segment into exact per-tile segments (proven).
__global__ void __launch_bounds__(256) k_pass2(
        const unsigned* __restrict__ recs1, const int* __restrict__ gcur,
        int cap1, int cap2, int* __restrict__ tcur, unsigned* __restrict__ recs2,
        int* __restrict__ ovfcur, uint2* __restrict__ ovfrecs) {
    __shared__ unsigned buf[NTX2][FB2];
    __shared__ int cnt[NTX2];
    int band = blockIdx.x / CPB;
    int chunk = blockIdx.x % CPB;
    int c1 = min(gcur[band * PAD], cap1);
    int chunklen = (((c1 + CPB - 1) / CPB) + 3) & ~3;
    int start = chunk * chunklen;
    int end = min(start + chunklen, c1);
    const unsigned* seg = recs1 + (size_t)band * cap1;
    for (int t = threadIdx.x; t < NTX2; t += 256) cnt[t] = 0;
    __syncthreads();
    int iters = (end > start) ? ((end - start + 1023) >> 10) : 0;
    int wave = threadIdx.x >> 6, lane = threadIdx.x & 63;
    for (int it = 0; it < iters; it++) {
        int idx = start + (it << 10) + (int)threadIdx.x * 4;
        unsigned r4[4];
        int m = 0;
        if (idx + 4 <= end) {
            uint4 q = *(const uint4*)&seg[idx];
            r4[0] = q.x; r4[1] = q.y; r4[2] = q.z; r4[3] = q.w; m = 4;
        } else {
            for (; idx + m < end && m < 4; m++) r4[m] = seg[idx + m];
        }
        #pragma unroll
        for (int k = 0; k < 4; k++) {
            if (k < m) {
                unsigned r = r4[k];
                int tx = min((int)((r >> 19) & 31u), NTX2 - 1);  // defensive
                int pos = atomicAdd(&cnt[tx], 1);
                if (pos < FB2) buf[tx][pos] = r;
                else spill_rec(r, band, ovfcur, ovfrecs);
            }
        }
        __syncthreads();
        bool last = (it == iters - 1);
        for (int bb = wave; bb < NTX2; bb += 4) {
            int c = min(cnt[bb], FB2);
            if (c >= (last ? 1 : FT2)) {
                int base = 0;
                if (lane == 0) base = atomicAdd(&tcur[(band * NTX2 + bb) * PAD], c);
                base = __shfl(base, 0, 64);
                for (int j = lane; j < c; j += 64) {
                    unsigned r = buf[bb][j];
                    int o = base + j;
                    if (o < cap2) recs2[(size_t)(band * NTX2 + bb) * cap2 + o] = r;
                    else spill_rec(r, band, ovfcur, ovfrecs);
                }
                if (lane == 0) cnt[bb] = 0;
            }
        }
        __syncthreads();
    }
}

// K4 v3: one block per 32x4 tile, exact segment, float4 stores, and per-bin
// partials PLAIN-STORED to a private slot (no contended global atomics).
__global__ void __launch_bounds__(256) k_accum5(
        const unsigned* __restrict__ recs2, const int* __restrict__ tcur,
        int nb, int cap2, float* __restrict__ out, double2* __restrict__ part2) {
    extern __shared__ float acc[];  // nb * 128
    int T = blockIdx.x;
    int ry = T / NTX2, tx = T % NTX2;
    int nacc4 = nb << 5;  // (nb*128)/4 float4s
    float4* acc4 = (float4*)acc;
    float4 z4 = make_float4(0.f, 0.f, 0.f, 0.f);
    for (int i = threadIdx.x; i < nacc4; i += 256) acc4[i] = z4;
    __syncthreads();
    int c2 = min(tcur[T * PAD], cap2);
    const unsigned* seg = recs2 + (size_t)T * cap2;
    int iters = (c2 + 1023) >> 10;
    for (int it = 0; it < iters; it++) {
        int idx = (it << 10) + (int)threadIdx.x * 4;
        unsigned r4[4];
        int m = 0;
        if (idx + 4 <= c2) {
            uint4 q = *(const uint4*)&seg[idx];
            r4[0] = q.x; r4[1] = q.y; r4[2] = q.z; r4[3] = q.w; m = 4;
        } else {
            for (; idx + m < c2 && m < 4; m++) r4[m] = seg[idx + m];
        }
        #pragma unroll
        for (int k = 0; k < 4; k++) {
            if (k < m) {
                unsigned r = r4[k];
                int b = min((int)((r >> 24) & 127u), nb - 1);
                int b1 = min(b + 1, nb - 1);
                int pix = (int)((r >> 12) & 127u);
                unsigned sgn = r & 0x80000000u;
                float wt = __fmul_rn((float)(r & 4095u), 2.44140625e-4f);  // /4096
                float w0 = __uint_as_float(__float_as_uint(__fsub_rn(1.0f, wt)) ^ sgn);
                float w1 = __uint_as_float(__float_as_uint(wt) ^ sgn);
                atomicAdd(&acc[(b << 7) + pix], w0);
                atomicAdd(&acc[(b1 << 7) + pix], w1);
            }
        }
    }
    __syncthreads();
    int x0 = tx * 32, y0 = ry * 4;
    // float4 store: i = b*32 + q; row = q>>3, qx = q&7
    for (int i = threadIdx.x; i < nacc4; i += 256) {
        int b = i >> 5;
        int q = i & 31;
        int row = q >> 3, qx = q & 7;
        *(float4*)&out[(size_t)b * HW_ + (size_t)(y0 + row) * W_ + x0 + (qx << 2)] = acc4[i];
    }
    // per-bin partials: thread t = 2*b + half sums 64 px (bank-staggered),
    // plain double2 store to this block's slot — zero atomic contention.
    int t = threadIdx.x;
    if (t < 2 * nb) {
        int b = t >> 1, half = t & 1;
        double s = 0.0, ss = 0.0;
        int basei = (b << 7) + (half << 6);
        for (int jj = 0; jj < 64; jj++) {
            float v = acc[basei + ((jj + b) & 63)];
            double dv = (double)v;
            s += dv; ss += dv * dv;
        }
        part2[(size_t)t * NT2 + T] = make_double2(s, ss);
    }
}

// K4c: reduce per-block partials -> sumv/sumsq. One block per bin.
__global__ void __launch_bounds__(256) k_redsum(
        const double2* __restrict__ part2, int nb,
        double* __restrict__ sumv, double* __restrict__ sumsq) {
    int b = blockIdx.x;
    const double2* r0 = part2 + (size_t)(2 * b) * NT2;
    const double2* r1 = part2 + (size_t)(2 * b + 1) * NT2;
    double s = 0.0, ss = 0.0;
    for (int i = threadIdx.x; i < NT2; i += 256) {
        double2 a = r0[i];
        double2 c = r1[i];
        s += a.x + c.x; ss += a.y + c.y;
    }
    #pragma unroll
    for (int off = 32; off > 0; off >>= 1) {
        s += __shfl_down(s, off, 64);
        ss += __shfl_down(ss, off, 64);
    }
    __shared__ double sb[4], sb2[4];
    int wave = threadIdx.x >> 6, lane = threadIdx.x & 63;
    if (lane == 0) { sb[wave] = s; sb2[wave] = ss; }
    __syncthreads();
    if (threadIdx.x == 0) {
        for (int i = 1; i < 4; i++) { s += sb[i]; ss += sb2[i]; }
        sumv[b] = s; sumsq[b] = ss;
    }
}

// K4b (filter fallback, proven round 7): one block per tile, scans band segment.
__global__ void __launch_bounds__(256) k_accum2(
        const unsigned* __restrict__ recs1, const int* __restrict__ gcur,
        int nb, int cap1, float* __restrict__ out,
        double* __restrict__ sumv, double* __restrict__ sumsq) {
    extern __shared__ float acc[];
    int h = blockIdx.x;
    int xcd = h & 7;
    int j = h >> 3;
    int kk2 = j / NTX2;
    int tx = j % NTX2;
    int ry = xcd + 8 * kk2;
    int nacc = nb * TPX2;
    for (int i = threadIdx.x; i < nacc; i += 256) acc[i] = 0.f;
    __syncthreads();
    int c1 = min(gcur[ry * PAD], cap1);
    const unsigned* seg = recs1 + (size_t)ry * cap1;
    unsigned txu = (unsigned)tx;
    int iters = (c1 + 1023) >> 10;
    for (int it = 0; it < iters; it++) {
        int idx = (it << 10) + (int)threadIdx.x * 4;
        unsigned r4[4];
        int m = 0;
        if (idx + 4 <= c1) {
            uint4 q = *(const uint4*)&seg[idx];
            r4[0] = q.x; r4[1] = q.y; r4[2] = q.z; r4[3] = q.w; m = 4;
        } else {
            for (; idx + m < c1 && m < 4; m++) r4[m] = seg[idx + m];
        }
        #pragma unroll
        for (int k = 0; k < 4; k++) {
            if (k < m) {
                unsigned r = r4[k];
                if (((r >> 19) & 31u) == txu) {
                    int b = min((int)((r >> 24) & 127u), nb - 1);
                    int b1 = min(b + 1, nb - 1);
                    int pix = (int)((r >> 12) & 127u);
                    unsigned sgn = r & 0x80000000u;
                    float wt = __fmul_rn((float)(r & 4095u), 2.44140625e-4f);
                    float w0 = __uint_as_float(__float_as_uint(__fsub_rn(1.0f, wt)) ^ sgn);
                    float w1 = __uint_as_float(__float_as_uint(wt) ^ sgn);
                    atomicAdd(&acc[b * TPX2 + pix], w0);
                    atomicAdd(&acc[b1 * TPX2 + pix], w1);
                }
            }
        }
    }
    __syncthreads();
    int x0 = tx * 32, y0 = ry * 4;
    for (int i = threadIdx.x; i < nacc; i += 256) {
        int b = i >> 7, p = i & 127;
        int yy = y0 + (p >> 5), xx = x0 + (p & 31);
        out[(size_t)b * HW_ + yy * W_ + xx] = acc[i];
    }
    if ((int)threadIdx.x < nb) {
        int b = threadIdx.x;
        double s = 0.0, ss = 0.0;
        for (int j2 = 0; j2 < TPX2; j2++) {
            float v = acc[b * TPX2 + ((j2 + b) & 127)];
            double dv = (double)v;
            s += dv; ss += dv * dv;
        }
        atomicAdd(&sumv[b], s);
        atomicAdd(&sumsq[b], ss);
    }
}

// K5: replay overflow with direct atomics AFTER accumulation+redsum; compensates
// sums exactly via the old value returned by the atomic RMW.
__global__ void k_ovf(const uint2* __restrict__ ovfrecs, const int* __restrict__ ovfcur,
                      int nb, float* __restrict__ out,
                      double* __restrict__ sumv, double* __restrict__ sumsq) {
    int m = min(*ovfcur, OVF);
    int tid = blockIdx.x * blockDim.x + threadIdx.x;
    int stride = gridDim.x * blockDim.x;
    for (int i = tid; i < m; i += stride) {
        uint2 r = ovfrecs[i];
        unsigned sgn = r.x & 0x80000000u;
        int b = (int)((r.x >> 20) & 511u);
        int sp = (int)(r.x & 0x7FFFFu);
        b = min(b, nb - 1); sp = min(sp, HW_ - 1);
        int b1 = min(b + 1, nb - 1);
        float wt = __uint_as_float(r.y);
        float w0 = __uint_as_float(__float_as_uint(__fsub_rn(1.0f, wt)) ^ sgn);
        float w1 = __uint_as_float(r.y ^ sgn);
        float o0 = unsafeAtomicAdd(out + (size_t)b * HW_ + sp, w0);
        atomicAdd(&sumv[b], (double)w0);
        atomicAdd(&sumsq[b], (double)w0 * ((double)w0 + 2.0 * (double)o0));
        float o1 = unsafeAtomicAdd(out + (size_t)b1 * HW_ + sp, w1);
        atomicAdd(&sumv[b1], (double)w1);
        atomicAdd(&sumsq[b1], (double)w1 * ((double)w1 + 2.0 * (double)o1));
    }
}

// ---- slow fallback: round-1 unsorted scatter (proven, ~1000us) ----
__global__ void k_scatter(const float* __restrict__ x, const float* __restrict__ y,
                          const float* __restrict__ ts, const float* __restrict__ pol,
                          const float* __restrict__ params, const float* __restrict__ bwp,
                          int n, int nb, const unsigned* __restrict__ minbits,
                          float* __restrict__ out) {
    float p0 = params[0], p1 = params[1];
    float bw = bwp[0];
    float tstart = finv(*minbits);
    float nbm1 = (float)(nb - 1);
    int tid = blockIdx.x * blockDim.x + threadIdx.x;
    int stride = gridDim.x * blockDim.x;
    for (int i = tid; i < n; i += stride) {
        float xf = x[i], yf = y[i];
        float tn = __fdiv_rn(__fsub_rn(warp_t(ts[i], xf, yf, p0, p1), tstart), bw);
        float t0f = floorf(tn);
        float wt = __fsub_rn(tn, t0f);
        int t0c = (int)fminf(fmaxf(t0f, 0.0f), nbm1);
        int t1c = (int)fminf(fmaxf(__fadd_rn(t0f, 1.0f), 0.0f), nbm1);
        int xi = (int)xf, yi = (int)yf;
        if (xi >= 0 && xi < W_ && yi >= 0 && yi < H_) {
            int sp = yi * W_ + xi;
            float p = pol[i];
            float w0 = __fmul_rn(__fsub_rn(1.0f, wt), p);
            float w1 = __fmul_rn(wt, p);
            unsafeAtomicAdd(&out[(size_t)t0c * HW_ + sp], w0);
            unsafeAtomicAdd(&out[(size_t)t1c * HW_ + sp], w1);
        }
    }
}

// K6 (slow fallback only): per-bin sum/sumsq in double
__global__ void k_sums(const float* __restrict__ out, double* __restrict__ sumv,
                       double* __restrict__ sumsq) {
    int b = blockIdx.x / VAR_SPLIT;
    int part = blockIdx.x % VAR_SPLIT;
    const int chunk = HW_ / VAR_SPLIT;
    const float* p = out + (size_t)b * HW_ + (size_t)part * chunk;
    double s = 0.0, ss = 0.0;
    for (int i = threadIdx.x; i < chunk; i += blockDim.x) {
        double v = (double)p[i];
        s += v; ss += v * v;
    }
    #pragma unroll
    for (int off = 32; off > 0; off >>= 1) {
        s += __shfl_down(s, off, 64);
        ss += __shfl_down(ss, off, 64);
    }
    __shared__ double sb[8], sb2[8];
    int wave = threadIdx.x >> 6, lane = threadIdx.x & 63;
    if (lane == 0) { sb[wave] = s; sb2[wave] = ss; }
    __syncthreads();
    if (threadIdx.x == 0) {
        int nw = blockDim.x >> 6;
        for (int i = 1; i < nw; i++) { s += sb[i]; ss += sb2[i]; }
        atomicAdd(&sumv[b], s);
        atomicAdd(&sumsq[b], ss);
    }
}

// K7: variance per bin (ddof=1), mean -> loss
__global__ void k_final(const double* __restrict__ sumv, const double* __restrict__ sumsq,
                        int nb, float* __restrict__ loss) {
    double acc = 0.0;
    const double n = (double)HW_;
    for (int b = threadIdx.x; b < nb; b += blockDim.x) {
        double s = sumv[b], ss = sumsq[b];
        acc += (ss - s * s / n) / (n - 1.0);
    }
    #pragma unroll
    for (int off = 32; off > 0; off >>= 1) acc += __shfl_down(acc, off, 64);
    __shared__ double sb[8];
    int wave = threadIdx.x >> 6, lane = threadIdx.x & 63;
    if (lane == 0) sb[wave] = acc;
    __syncthreads();
    if (threadIdx.x == 0) {
        int nw = blockDim.x >> 6;
        for (int i = 1; i < nw; i++) acc += sb[i];
        *loss = (float)(acc / (double)nb);
    }
}

extern "C" void kernel_launch(void* const* d_in, const int* in_sizes, int n_in,
                              void* d_out, int out_size, void* d_ws, size_t ws_size,
                              hipStream_t stream) {
    const float* params = (const float*)d_in[0];
    const float* x      = (const float*)d_in[1];
    const float* y      = (const float*)d_in[2];
    const float* ts     = (const float*)d_in[3];
    const float* pol    = (const float*)d_in[4];
    const float* bwp    = (const float*)d_in[7];

    int n  = in_sizes[1];
    int nb = (out_size - 1) / HW_;
    float* out = (float*)d_out;

    // ws layout: minbits | ovfcur | sumv,sumsq | gcur[120*PAD] | tcur[2400*PAD]
    //            | part2[2*nb][NT2] double2 | ovfrecs[OVF] | recs1 | recs2
    size_t off_sums  = 128;
    size_t off_gcur  = (off_sums + 16ULL * nb + 63) & ~(size_t)63;
    size_t off_tcur  = off_gcur + 4ULL * NBAND * PAD;
    size_t off_part  = (off_tcur + 4ULL * NT2 * PAD + 63) & ~(size_t)63;
    size_t off_ovfr  = (off_part + 16ULL * 2 * nb * NT2 + 63) & ~(size_t)63;
    size_t off_recs1 = (off_ovfr + 8ULL * OVF + 63) & ~(size_t)63;

    unsigned* minbits = (unsigned*)d_ws;
    int*      ovfcur  = (int*)((char*)d_ws + 64);
    double*   sumv    = (double*)((char*)d_ws + off_sums);
    double*   sumsq   = sumv + nb;
    int*      gcur    = (int*)((char*)d_ws + off_gcur);
    int*      tcur    = (int*)((char*)d_ws + off_tcur);
    double2*  part2   = (double2*)((char*)d_ws + off_part);
    uint2*    ovfrecs = (uint2*)((char*)d_ws + off_ovfr);
    unsigned* recs1   = (unsigned*)((char*)d_ws + off_recs1);

    long long mean1 = (long long)n / NBAND;
    long long mean2 = (long long)n / NT2;

    // exact path: fixed cap1, adaptive cap2
    long long cap1e = (mean1 + mean1 / 8 + 2048) & ~3LL;
    size_t off_recs2 = (off_recs1 + 4ULL * NBAND * cap1e + 63) & ~(size_t)63;
    unsigned* recs2 = (unsigned*)((char*)d_ws + off_recs2);
    long long avail2 = (ws_size > off_recs2)
                       ? (long long)((ws_size - off_recs2) / (4ULL * NT2)) : 0;
    long long cap2min = mean2 + mean2 / 8 + 256;
    long long cap2max = 2 * mean2 + 1024;
    long long cap2ll = ((avail2 < cap2max) ? avail2 : cap2max) & ~3LL;
    bool exact = (n > 0) && (nb >= 1) && (nb <= MAXNB_T) && (cap2ll >= cap2min);

    // filter path (round-7): bigger cap1 allowed, no recs2 (part region unused)
    long long avail1 = (ws_size > off_recs1)
                       ? (long long)((ws_size - off_recs1) / (4ULL * NBAND)) : 0;
    long long cap1f_max = 2 * mean1 + 4096;
    long long cap1fll = ((avail1 < cap1f_max) ? avail1 : cap1f_max) & ~3LL;
    bool filter = !exact && (n > 0) && (nb >= 1) && (nb <= MAXNB_T) &&
                  (cap1fll >= mean1 + mean1 / 12 + 2048);

    int cap1 = (int)(exact ? cap1e : cap1fll);
    int cap2 = (int)cap2ll;

    int n_tensor = nb * HW_;
    int n4 = (exact || filter) ? 0 : (n_tensor >> 2);

    const int BLK = 256;
    const int G1 = 1280;
    const int ITBLK = EPT1 * 256;
    int per = (((n + G1 - 1) / G1) + ITBLK - 1) / ITBLK * ITBLK;
    int g1used = (n + per - 1) / per;

    hipLaunchKernelGGL(k_init, dim3(2048), dim3(BLK), 0, stream,
                       out, n4, minbits, ovfcur, sumv, 2 * nb,
                       gcur, NBAND * PAD + NT2 * PAD);
    hipLaunchKernelGGL(k_min, dim3(2048), dim3(BLK), 0, stream,
                       x, y, ts, params, n, minbits);

    if (exact) {
        hipLaunchKernelGGL(k_pass1, dim3(g1used), dim3(BLK), 0, stream,
                           x, y, ts, pol, params, bwp, n, nb, cap1, per, minbits,
                           gcur, recs1, ovfcur, ovfrecs);
        hipLaunchKernelGGL(k_pass2, dim3(NBAND * CPB), dim3(BLK), 0, stream,
                           recs1, gcur, cap1, cap2, tcur, recs2, ovfcur, ovfrecs);
        hipLaunchKernelGGL(k_accum5, dim3(NT2), dim3(BLK), (size_t)nb * TPX2 * 4, stream,
                           recs2, tcur, nb, cap2, out, part2);
        hipLaunchKernelGGL(k_redsum, dim3(nb), dim3(BLK), 0, stream,
                           part2, nb, sumv, sumsq);
        hipLaunchKernelGGL(k_ovf, dim3(64), dim3(BLK), 0, stream,
                           ovfrecs, ovfcur, nb, out, sumv, sumsq);
    } else if (filter) {
        hipLaunchKernelGGL(k_pass1, dim3(g1used), dim3(BLK), 0, stream,
                           x, y, ts, pol, params, bwp, n, nb, cap1, per, minbits,
                           gcur, recs1, ovfcur, ovfrecs);
        hipLaunchKernelGGL(k_accum2, dim3(NT2), dim3(BLK), (size_t)nb * TPX2 * 4, stream,
                           recs1, gcur, nb, cap1, out, sumv, sumsq);
        hipLaunchKernelGGL(k_ovf, dim3(64), dim3(BLK), 0, stream,
                           ovfrecs, ovfcur, nb, out, sumv, sumsq);
    } else {
        hipLaunchKernelGGL(k_scatter, dim3(2048), dim3(BLK), 0, stream,
                           x, y, ts, pol, params, bwp, n, nb, minbits, out);
        hipLaunchKernelGGL(k_sums, dim3(nb * VAR_SPLIT), dim3(BLK), 0, stream,
                           out, sumv, sumsq);
    }

    hipLaunchKernelGGL(k_final, dim3(1), dim3(BLK), 0, stream,
                       sumv, sumsq, nb, out + n_tensor);
}

// Round 11
// 361.945 us; speedup vs baseline: 1.1855x; 1.0129x over previous
//
#include <hip/hip_runtime.h>

#define W_ 640
#define H_ 480
#define HW_ (W_ * H_)
#define VAR_SPLIT 8
#define MAXNB_T 124         // bin fits 7 bits; accum5 LDS nb*512B <= 63.5KB
#define NBAND 120           // 4-px-high bands
#define NTX2 20             // 32-px-wide tiles per band
#define NT2 (NBAND * NTX2)  // 2400 tiles
#define TPX2 128            // 32x4 pixels per tile
#define FB 48               // pass1 LDS records per band bucket
#define FT 32               // pass1 flush threshold
#define FB2 256             // pass2 LDS records per tile bucket
#define FT2 128             // pass2 flush threshold
#define PAD 16              // ints per cursor (64B line)
#define OVF 131072
#define CPB 8               // pass2 chunks per band

// ---- order-preserving float <-> uint key for atomic min ----
__device__ __forceinline__ unsigned fkey(float f) {
    unsigned u = __float_as_uint(f);
    return (u & 0x80000000u) ? ~u : (u | 0x80000000u);
}
__device__ __forceinline__ float finv(unsigned k) {
    unsigned u = (k & 0x80000000u) ? (k ^ 0x80000000u) : ~k;
    return __uint_as_float(u);
}
__device__ __forceinline__ float warp_t(float ts, float xf, float yf, float p0, float p1) {
    return __fsub_rn(__fsub_rn(ts, __fmul_rn(p0, xf)), __fmul_rn(p1, yf));
}

// exact-payload spill of a packed band record (band needed to rebuild coords)
__device__ __forceinline__ void spill_rec(unsigned r, int band,
                                          int* ovfcur, uint2* ovfrecs) {
    int j = atomicAdd(ovfcur, 1);
    if (j < OVF) {
        int pix = (int)((r >> 12) & 127u);
        int yi = band * 4 + (pix >> 5);
        int xi = (int)((r >> 19) & 31u) * 32 + (pix & 31);
        int b = (int)((r >> 24) & 127u);
        float wt = __fmul_rn((float)(r & 4095u), 2.44140625e-4f);
        unsigned px = ((unsigned)b << 20) | (unsigned)(yi * W_ + xi) | (r & 0x80000000u);
        ovfrecs[j] = make_uint2(px, __float_as_uint(wt));
    }
}

// K0: init. out zeroing only on slow path (fast paths overwrite every cell).
__global__ void k_init(float* __restrict__ out, int n4, unsigned* __restrict__ minbits,
                       int* __restrict__ ovfcur, double* __restrict__ sums, int nsums,
                       int* __restrict__ curs, int ncur) {
    int tid = blockIdx.x * blockDim.x + threadIdx.x;
    int stride = gridDim.x * blockDim.x;
    float4* o4 = (float4*)out;
    float4 z = make_float4(0.f, 0.f, 0.f, 0.f);
    for (int i = tid; i < n4; i += stride) o4[i] = z;
    for (int i = tid; i < ncur; i += stride) curs[i] = 0;
    if (tid == 0) { *minbits = 0xFFFFFFFFu; *ovfcur = 0; }
    if (tid < nsums) sums[tid] = 0.0;
}

// K1 v2: global min of t_warped — float4 vectorized loads (4 events / 3 requests).
__global__ void k_min(const float* __restrict__ x, const float* __restrict__ y,
                      const float* __restrict__ ts, const float* __restrict__ params,
                      int n, unsigned* __restrict__ minbits) {
    float p0 = params[0], p1 = params[1];
    int tid = blockIdx.x * blockDim.x + threadIdx.x;
    int stride = gridDim.x * blockDim.x;
    int n4 = n >> 2;
    const float4* x4 = (const float4*)x;
    const float4* y4 = (const float4*)y;
    const float4* t4 = (const float4*)ts;
    unsigned k = 0xFFFFFFFFu;
    for (int i = tid; i < n4; i += stride) {
        float4 xv = x4[i], yv = y4[i], tv = t4[i];
        unsigned k0 = fkey(warp_t(tv.x, xv.x, yv.x, p0, p1));
        unsigned k1 = fkey(warp_t(tv.y, xv.y, yv.y, p0, p1));
        unsigned k2 = fkey(warp_t(tv.z, xv.z, yv.z, p0, p1));
        unsigned k3 = fkey(warp_t(tv.w, xv.w, yv.w, p0, p1));
        unsigned ka = min(k0, k1), kb = min(k2, k3);
        k = min(k, min(ka, kb));
    }
    for (int i = (n4 << 2) + tid; i < n; i += stride)
        k = min(k, fkey(warp_t(ts[i], x[i], y[i], p0, p1)));
    #pragma unroll
    for (int off = 32; off > 0; off >>= 1) {
        unsigned o = __shfl_down(k, off, 64);
        k = (o < k) ? o : k;
    }
    if ((threadIdx.x & 63) == 0) atomicMin(minbits, k);
}

// K2 v3: LDS-staged band bucketing, float4 vectorized event loads.
// Record: [31]sign [30:24]bin [23:19]tilex [18:12]pix [11:0]wq.
__global__ void __launch_bounds__(256) k_pass1(
        const float* __restrict__ x, const float* __restrict__ y,
        const float* __restrict__ ts, const float* __restrict__ pol,
        const float* __restrict__ params, const float* __restrict__ bwp,
        int n, int nb, int cap1, int per, const unsigned* __restrict__ minbits,
        int* __restrict__ gcur, unsigned* __restrict__ recs1,
        int* __restrict__ ovfcur, uint2* __restrict__ ovfrecs) {
    __shared__ unsigned buf[NBAND][FB];
    __shared__ int cnt[NBAND];
    float p0 = params[0], p1 = params[1], bw = bwp[0];
    float tstart = finv(*minbits);
    float nbm1 = (float)(nb - 1);
    for (int t = threadIdx.x; t < NBAND; t += 256) cnt[t] = 0;
    __syncthreads();
    int lo = blockIdx.x * per;          // per is a multiple of 1024 -> 16B aligned
    int hi = min(n, lo + per);
    int total = (hi > lo) ? (hi - lo) : 0;
    int nf4 = total >> 2;
    const float4* x4 = (const float4*)(x + lo);
    const float4* y4 = (const float4*)(y + lo);
    const float4* t4 = (const float4*)(ts + lo);
    const float4* p4 = (const float4*)(pol + lo);
    int wave = threadIdx.x >> 6, lane = threadIdx.x & 63;

    auto proc = [&](float xf, float yf, float tf, float pf) {
        int xi = (int)xf, yi = (int)yf;
        if (xi >= 0 && xi < W_ && yi >= 0 && yi < H_) {
            float tn = __fdiv_rn(__fsub_rn(warp_t(tf, xf, yf, p0, p1), tstart), bw);
            float t0f = floorf(tn);
            float wt = __fsub_rn(tn, t0f);
            int b = (int)fminf(fmaxf(t0f, 0.0f), nbm1);
            unsigned sgn = __float_as_uint(pf) & 0x80000000u;
            int band = yi >> 2;
            unsigned tilex = (unsigned)(xi >> 5);
            unsigned pix = (unsigned)(((yi & 3) << 5) | (xi & 31));
            unsigned wq = (unsigned)__fmul_rn(wt, 4096.0f);  // <= 4095
            unsigned rec = sgn | ((unsigned)b << 24) | (tilex << 19) | (pix << 12) | wq;
            int pos = atomicAdd(&cnt[band], 1);
            if (pos < FB) buf[band][pos] = rec;
            else {
                int j = atomicAdd(ovfcur, 1);
                if (j < OVF) {
                    unsigned px = ((unsigned)b << 20) | (unsigned)(yi * W_ + xi) | sgn;
                    ovfrecs[j] = make_uint2(px, __float_as_uint(wt));
                }
            }
        }
    };
    auto flush = [&](int thresh) {
        for (int bb = wave; bb < NBAND; bb += 4) {
            int c = min(cnt[bb], FB);
            if (c >= thresh) {
                int base = 0;
                if (lane == 0) base = atomicAdd(&gcur[bb * PAD], c);
                base = __shfl(base, 0, 64);
                for (int j = lane; j < c; j += 64) {
                    unsigned r = buf[bb][j];
                    int idx = base + j;
                    if (idx < cap1) recs1[(size_t)bb * cap1 + idx] = r;
                    else spill_rec(r, bb, ovfcur, ovfrecs);
                }
                if (lane == 0) cnt[bb] = 0;
            }
        }
    };

    int iters = (nf4 + 255) >> 8;
    for (int it = 0; it < iters; it++) {
        int i4 = (it << 8) + (int)threadIdx.x;
        bool valid = (i4 < nf4);
        float4 xv, yv, tv, pv;
        if (valid) { xv = x4[i4]; yv = y4[i4]; tv = t4[i4]; pv = p4[i4]; }
        if (valid) {
            proc(xv.x, yv.x, tv.x, pv.x);
            proc(xv.y, yv.y, tv.y, pv.y);
            proc(xv.z, yv.z, tv.z, pv.z);
            proc(xv.w, yv.w, tv.w, pv.w);
        }
        __syncthreads();
        flush(FT);
        __syncthreads();
    }
    // scalar tail (< 4 events) + final drain
    int tbase = lo + (nf4 << 2);
    int trem = hi - tbase;
    if ((int)threadIdx.x < trem) {
        int i = tbase + (int)threadIdx.x;
        proc(x[i], y[i], ts[i], pol[i]);
    }
    __syncthreads();
    flush(1);
}

// K3: sub-bucket each band segment into exact per-tile segments (proven).
__global__ void __launch_bounds__(256) k_pass2(
        const unsigned* __restrict__ recs1, const int* __restrict__ gcur,
        int cap1, int cap2, int* __restrict__ tcur, unsigned* __restrict__ recs2,
        int* __restrict__ ovfcur, uint2* __restrict__ ovfrecs) {
    __shared__ unsigned buf[NTX2][FB2];
    __shared__ int cnt[NTX2];
    int band = blockIdx.x / CPB;
    int chunk = blockIdx.x % CPB;
    int c1 = min(gcur[band * PAD], cap1);
    int chunklen = (((c1 + CPB - 1) / CPB) + 3) & ~3;
    int start = chunk * chunklen;
    int end = min(start + chunklen, c1);
    const unsigned* seg = recs1 + (size_t)band * cap1;
    for (int t = threadIdx.x; t < NTX2; t += 256) cnt[t] = 0;
    __syncthreads();
    int iters = (end > start) ? ((end - start + 1023) >> 10) : 0;
    int wave = threadIdx.x >> 6, lane = threadIdx.x & 63;
    for (int it = 0; it < iters; it++) {
        int idx = start + (it << 10) + (int)threadIdx.x * 4;
        unsigned r4[4];
        int m = 0;
        if (idx + 4 <= end) {
            uint4 q = *(const uint4*)&seg[idx];
            r4[0] = q.x; r4[1] = q.y; r4[2] = q.z; r4[3] = q.w; m = 4;
        } else {
            for (; idx + m < end && m < 4; m++) r4[m] = seg[idx + m];
        }
        #pragma unroll
        for (int k = 0; k < 4; k++) {
            if (k < m) {
                unsigned r = r4[k];
                int tx = min((int)((r >> 19) & 31u), NTX2 - 1);  // defensive
                int pos = atomicAdd(&cnt[tx], 1);
                if (pos < FB2) buf[tx][pos] = r;
                else spill_rec(r, band, ovfcur, ovfrecs);
            }
        }
        __syncthreads();
        bool last = (it == iters - 1);
        for (int bb = wave; bb < NTX2; bb += 4) {
            int c = min(cnt[bb], FB2);
            if (c >= (last ? 1 : FT2)) {
                int base = 0;
                if (lane == 0) base = atomicAdd(&tcur[(band * NTX2 + bb) * PAD], c);
                base = __shfl(base, 0, 64);
                for (int j = lane; j < c; j += 64) {
                    unsigned r = buf[bb][j];
                    int o = base + j;
                    if (o < cap2) recs2[(size_t)(band * NTX2 + bb) * cap2 + o] = r;
                    else spill_rec(r, band, ovfcur, ovfrecs);
                }
                if (lane == 0) cnt[bb] = 0;
            }
        }
        __syncthreads();
    }
}

// K4: one block per 32x4 tile, exact segment, float4 stores, per-bin partials
// plain-stored to private slots (no contended global atomics). (proven r10)
__global__ void __launch_bounds__(256) k_accum5(
        const unsigned* __restrict__ recs2, const int* __restrict__ tcur,
        int nb, int cap2, float* __restrict__ out, double2* __restrict__ part2) {
    extern __shared__ float acc[];  // nb * 128
    int T = blockIdx.x;
    int ry = T / NTX2, tx = T % NTX2;
    int nacc4 = nb << 5;
    float4* acc4 = (float4*)acc;
    float4 z4 = make_float4(0.f, 0.f, 0.f, 0.f);
    for (int i = threadIdx.x; i < nacc4; i += 256) acc4[i] = z4;
    __syncthreads();
    int c2 = min(tcur[T * PAD], cap2);
    const unsigned* seg = recs2 + (size_t)T * cap2;
    int iters = (c2 + 1023) >> 10;
    for (int it = 0; it < iters; it++) {
        int idx = (it << 10) + (int)threadIdx.x * 4;
        unsigned r4[4];
        int m = 0;
        if (idx + 4 <= c2) {
            uint4 q = *(const uint4*)&seg[idx];
            r4[0] = q.x; r4[1] = q.y; r4[2] = q.z; r4[3] = q.w; m = 4;
        } else {
            for (; idx + m < c2 && m < 4; m++) r4[m] = seg[idx + m];
        }
        #pragma unroll
        for (int k = 0; k < 4; k++) {
            if (k < m) {
                unsigned r = r4[k];
                int b = min((int)((r >> 24) & 127u), nb - 1);
                int b1 = min(b + 1, nb - 1);
                int pix = (int)((r >> 12) & 127u);
                unsigned sgn = r & 0x80000000u;
                float wt = __fmul_rn((float)(r & 4095u), 2.44140625e-4f);
                float w0 = __uint_as_float(__float_as_uint(__fsub_rn(1.0f, wt)) ^ sgn);
                float w1 = __uint_as_float(__float_as_uint(wt) ^ sgn);
                atomicAdd(&acc[(b << 7) + pix], w0);
                atomicAdd(&acc[(b1 << 7) + pix], w1);
            }
        }
    }
    __syncthreads();
    int x0 = tx * 32, y0 = ry * 4;
    for (int i = threadIdx.x; i < nacc4; i += 256) {
        int b = i >> 5;
        int q = i & 31;
        int row = q >> 3, qx = q & 7;
        *(float4*)&out[(size_t)b * HW_ + (size_t)(y0 + row) * W_ + x0 + (qx << 2)] = acc4[i];
    }
    int t = threadIdx.x;
    if (t < 2 * nb) {
        int b = t >> 1, half = t & 1;
        double s = 0.0, ss = 0.0;
        int basei = (b << 7) + (half << 6);
        for (int jj = 0; jj < 64; jj++) {
            float v = acc[basei + ((jj + b) & 63)];
            double dv = (double)v;
            s += dv; ss += dv * dv;
        }
        part2[(size_t)t * NT2 + T] = make_double2(s, ss);
    }
}

// K4c: reduce per-block partials -> sumv/sumsq. One block per bin. (proven r10)
__global__ void __launch_bounds__(256) k_redsum(
        const double2* __restrict__ part2, int nb,
        double* __restrict__ sumv, double* __restrict__ sumsq) {
    int b = blockIdx.x;
    const double2* r0 = part2 + (size_t)(2 * b) * NT2;
    const double2* r1 = part2 + (size_t)(2 * b + 1) * NT2;
    double s = 0.0, ss = 0.0;
    for (int i = threadIdx.x; i < NT2; i += 256) {
        double2 a = r0[i];
        double2 c = r1[i];
        s += a.x + c.x; ss += a.y + c.y;
    }
    #pragma unroll
    for (int off = 32; off > 0; off >>= 1) {
        s += __shfl_down(s, off, 64);
        ss += __shfl_down(ss, off, 64);
    }
    __shared__ double sb[4], sb2[4];
    int wave = threadIdx.x >> 6, lane = threadIdx.x & 63;
    if (lane == 0) { sb[wave] = s; sb2[wave] = ss; }
    __syncthreads();
    if (threadIdx.x == 0) {
        for (int i = 1; i < 4; i++) { s += sb[i]; ss += sb2[i]; }
        sumv[b] = s; sumsq[b] = ss;
    }
}

// K4b (filter fallback, proven round 7): one block per tile, scans band segment.
__global__ void __launch_bounds__(256) k_accum2(
        const unsigned* __restrict__ recs1, const int* __restrict__ gcur,
        int nb, int cap1, float* __restrict__ out,
        double* __restrict__ sumv, double* __restrict__ sumsq) {
    extern __shared__ float acc[];
    int h = blockIdx.x;
    int xcd = h & 7;
    int j = h >> 3;
    int kk2 = j / NTX2;
    int tx = j % NTX2;
    int ry = xcd + 8 * kk2;
    int nacc = nb * TPX2;
    for (int i = threadIdx.x; i < nacc; i += 256) acc[i] = 0.f;
    __syncthreads();
    int c1 = min(gcur[ry * PAD], cap1);
    const unsigned* seg = recs1 + (size_t)ry * cap1;
    unsigned txu = (unsigned)tx;
    int iters = (c1 + 1023) >> 10;
    for (int it = 0; it < iters; it++) {
        int idx = (it << 10) + (int)threadIdx.x * 4;
        unsigned r4[4];
        int m = 0;
        if (idx + 4 <= c1) {
            uint4 q = *(const uint4*)&seg[idx];
            r4[0] = q.x; r4[1] = q.y; r4[2] = q.z; r4[3] = q.w; m = 4;
        } else {
            for (; idx + m < c1 && m < 4; m++) r4[m] = seg[idx + m];
        }
        #pragma unroll
        for (int k = 0; k < 4; k++) {
            if (k < m) {
                unsigned r = r4[k];
                if (((r >> 19) & 31u) == txu) {
                    int b = min((int)((r >> 24) & 127u), nb - 1);
                    int b1 = min(b + 1, nb - 1);
                    int pix = (int)((r >> 12) & 127u);
                    unsigned sgn = r & 0x80000000u;
                    float wt = __fmul_rn((float)(r & 4095u), 2.44140625e-4f);
                    float w0 = __uint_as_float(__float_as_uint(__fsub_rn(1.0f, wt)) ^ sgn);
                    float w1 = __uint_as_float(__float_as_uint(wt) ^ sgn);
                    atomicAdd(&acc[b * TPX2 + pix], w0);
                    atomicAdd(&acc[b1 * TPX2 + pix], w1);
                }
            }
        }
    }
    __syncthreads();
    int x0 = tx * 32, y0 = ry * 4;
    for (int i = threadIdx.x; i < nacc; i += 256) {
        int b = i >> 7, p = i & 127;
        int yy = y0 + (p >> 5), xx = x0 + (p & 31);
        out[(size_t)b * HW_ + yy * W_ + xx] = acc[i];
    }
    if ((int)threadIdx.x < nb) {
        int b = threadIdx.x;
        double s = 0.0, ss = 0.0;
        for (int j2 = 0; j2 < TPX2; j2++) {
            float v = acc[b * TPX2 + ((j2 + b) & 127)];
            double dv = (double)v;
            s += dv; ss += dv * dv;
        }
        atomicAdd(&sumv[b], s);
        atomicAdd(&sumsq[b], ss);
    }
}

// K5: replay overflow with direct atomics AFTER accumulation+redsum; compensates
// sums exactly via the old value returned by the atomic RMW.
__global__ void k_ovf(const uint2* __restrict__ ovfrecs, const int* __restrict__ ovfcur,
                      int nb, float* __restrict__ out,
                      double* __restrict__ sumv, double* __restrict__ sumsq) {
    int m = min(*ovfcur, OVF);
    int tid = blockIdx.x * blockDim.x + threadIdx.x;
    int stride = gridDim.x * blockDim.x;
    for (int i = tid; i < m; i += stride) {
        uint2 r = ovfrecs[i];
        unsigned sgn = r.x & 0x80000000u;
        int b = (int)((r.x >> 20) & 511u);
        int sp = (int)(r.x & 0x7FFFFu);
        b = min(b, nb - 1); sp = min(sp, HW_ - 1);
        int b1 = min(b + 1, nb - 1);
        float wt = __uint_as_float(r.y);
        float w0 = __uint_as_float(__float_as_uint(__fsub_rn(1.0f, wt)) ^ sgn);
        float w1 = __uint_as_float(r.y ^ sgn);
        float o0 = unsafeAtomicAdd(out + (size_t)b * HW_ + sp, w0);
        atomicAdd(&sumv[b], (double)w0);
        atomicAdd(&sumsq[b], (double)w0 * ((double)w0 + 2.0 * (double)o0));
        float o1 = unsafeAtomicAdd(out + (size_t)b1 * HW_ + sp, w1);
        atomicAdd(&sumv[b1], (double)w1);
        atomicAdd(&sumsq[b1], (double)w1 * ((double)w1 + 2.0 * (double)o1));
    }
}

// ---- slow fallback: round-1 unsorted scatter (proven, ~1000us) ----
__global__ void k_scatter(const float* __restrict__ x, const float* __restrict__ y,
                          const float* __restrict__ ts, const float* __restrict__ pol,
                          const float* __restrict__ params, const float* __restrict__ bwp,
                          int n, int nb, const unsigned* __restrict__ minbits,
                          float* __restrict__ out) {
    float p0 = params[0], p1 = params[1];
    float bw = bwp[0];
    float tstart = finv(*minbits);
    float nbm1 = (float)(nb - 1);
    int tid = blockIdx.x * blockDim.x + threadIdx.x;
    int stride = gridDim.x * blockDim.x;
    for (int i = tid; i < n; i += stride) {
        float xf = x[i], yf = y[i];
        float tn = __fdiv_rn(__fsub_rn(warp_t(ts[i], xf, yf, p0, p1), tstart), bw);
        float t0f = floorf(tn);
        float wt = __fsub_rn(tn, t0f);
        int t0c = (int)fminf(fmaxf(t0f, 0.0f), nbm1);
        int t1c = (int)fminf(fmaxf(__fadd_rn(t0f, 1.0f), 0.0f), nbm1);
        int xi = (int)xf, yi = (int)yf;
        if (xi >= 0 && xi < W_ && yi >= 0 && yi < H_) {
            int sp = yi * W_ + xi;
            float p = pol[i];
            float w0 = __fmul_rn(__fsub_rn(1.0f, wt), p);
            float w1 = __fmul_rn(wt, p);
            unsafeAtomicAdd(&out[(size_t)t0c * HW_ + sp], w0);
            unsafeAtomicAdd(&out[(size_t)t1c * HW_ + sp], w1);
        }
    }
}

// K6 (slow fallback only): per-bin sum/sumsq in double
__global__ void k_sums(const float* __restrict__ out, double* __restrict__ sumv,
                       double* __restrict__ sumsq) {
    int b = blockIdx.x / VAR_SPLIT;
    int part = blockIdx.x % VAR_SPLIT;
    const int chunk = HW_ / VAR_SPLIT;
    const float* p = out + (size_t)b * HW_ + (size_t)part * chunk;
    double s = 0.0, ss = 0.0;
    for (int i = threadIdx.x; i < chunk; i += blockDim.x) {
        double v = (double)p[i];
        s += v; ss += v * v;
    }
    #pragma unroll
    for (int off = 32; off > 0; off >>= 1) {
        s += __shfl_down(s, off, 64);
        ss += __shfl_down(ss, off, 64);
    }
    __shared__ double sb[8], sb2[8];
    int wave = threadIdx.x >> 6, lane = threadIdx.x & 63;
    if (lane == 0) { sb[wave] = s; sb2[wave] = ss; }
    __syncthreads();
    if (threadIdx.x == 0) {
        int nw = blockDim.x >> 6;
        for (int i = 1; i < nw; i++) { s += sb[i]; ss += sb2[i]; }
        atomicAdd(&sumv[b], s);
        atomicAdd(&sumsq[b], ss);
    }
}

// K7: variance per bin (ddof=1), mean -> loss
__global__ void k_final(const double* __restrict__ sumv, const double* __restrict__ sumsq,
                        int nb, float* __restrict__ loss) {
    double acc = 0.0;
    const double n = (double)HW_;
    for (int b = threadIdx.x; b < nb; b += blockDim.x) {
        double s = sumv[b], ss = sumsq[b];
        acc += (ss - s * s / n) / (n - 1.0);
    }
    #pragma unroll
    for (int off = 32; off > 0; off >>= 1) acc += __shfl_down(acc, off, 64);
    __shared__ double sb[8];
    int wave = threadIdx.x >> 6, lane = threadIdx.x & 63;
    if (lane == 0) sb[wave] = acc;
    __syncthreads();
    if (threadIdx.x == 0) {
        int nw = blockDim.x >> 6;
        for (int i = 1; i < nw; i++) acc += sb[i];
        *loss = (float)(acc / (double)nb);
    }
}

extern "C" void kernel_launch(void* const* d_in, const int* in_sizes, int n_in,
                              void* d_out, int out_size, void* d_ws, size_t ws_size,
                              hipStream_t stream) {
    const float* params = (const float*)d_in[0];
    const float* x      = (const float*)d_in[1];
    const float* y      = (const float*)d_in[2];
    const float* ts     = (const float*)d_in[3];
    const float* pol    = (const float*)d_in[4];
    const float* bwp    = (const float*)d_in[7];

    int n  = in_sizes[1];
    int nb = (out_size - 1) / HW_;
    float* out = (float*)d_out;

    // ws layout: minbits | ovfcur | sumv,sumsq | gcur[120*PAD] | tcur[2400*PAD]
    //            | part2[2*nb][NT2] double2 | ovfrecs[OVF] | recs1 | recs2
    size_t off_sums  = 128;
    size_t off_gcur  = (off_sums + 16ULL * nb + 63) & ~(size_t)63;
    size_t off_tcur  = off_gcur + 4ULL * NBAND * PAD;
    size_t off_part  = (off_tcur + 4ULL * NT2 * PAD + 63) & ~(size_t)63;
    size_t off_ovfr  = (off_part + 16ULL * 2 * nb * NT2 + 63) & ~(size_t)63;
    size_t off_recs1 = (off_ovfr + 8ULL * OVF + 63) & ~(size_t)63;

    unsigned* minbits = (unsigned*)d_ws;
    int*      ovfcur  = (int*)((char*)d_ws + 64);
    double*   sumv    = (double*)((char*)d_ws + off_sums);
    double*   sumsq   = sumv + nb;
    int*      gcur    = (int*)((char*)d_ws + off_gcur);
    int*      tcur    = (int*)((char*)d_ws + off_tcur);
    double2*  part2   = (double2*)((char*)d_ws + off_part);
    uint2*    ovfrecs = (uint2*)((char*)d_ws + off_ovfr);
    unsigned* recs1   = (unsigned*)((char*)d_ws + off_recs1);

    long long mean1 = (long long)n / NBAND;
    long long mean2 = (long long)n / NT2;

    long long cap1e = (mean1 + mean1 / 8 + 2048) & ~3LL;
    size_t off_recs2 = (off_recs1 + 4ULL * NBAND * cap1e + 63) & ~(size_t)63;
    unsigned* recs2 = (unsigned*)((char*)d_ws + off_recs2);
    long long avail2 = (ws_size > off_recs2)
                       ? (long long)((ws_size - off_recs2) / (4ULL * NT2)) : 0;
    long long cap2min = mean2 + mean2 / 8 + 256;
    long long cap2max = 2 * mean2 + 1024;
    long long cap2ll = ((avail2 < cap2max) ? avail2 : cap2max) & ~3LL;
    bool exact = (n > 0) && (nb >= 1) && (nb <= MAXNB_T) && (cap2ll >= cap2min);

    long long avail1 = (ws_size > off_recs1)
                       ? (long long)((ws_size - off_recs1) / (4ULL * NBAND)) : 0;
    long long cap1f_max = 2 * mean1 + 4096;
    long long cap1fll = ((avail1 < cap1f_max) ? avail1 : cap1f_max) & ~3LL;
    bool filter = !exact && (n > 0) && (nb >= 1) && (nb <= MAXNB_T) &&
                  (cap1fll >= mean1 + mean1 / 12 + 2048);

    int cap1 = (int)(exact ? cap1e : cap1fll);
    int cap2 = (int)cap2ll;

    int n_tensor = nb * HW_;
    int n4 = (exact || filter) ? 0 : (n_tensor >> 2);

    const int BLK = 256;
    const int G1 = 1280;
    const int ITBLK = 1024;  // 256 threads x 4 events (float4)
    int per = (((n + G1 - 1) / G1) + ITBLK - 1) / ITBLK * ITBLK;
    int g1used = (n + per - 1) / per;

    hipLaunchKernelGGL(k_init, dim3(2048), dim3(BLK), 0, stream,
                       out, n4, minbits, ovfcur, sumv, 2 * nb,
                       gcur, NBAND * PAD + NT2 * PAD);
    hipLaunchKernelGGL(k_min, dim3(2048), dim3(BLK), 0, stream,
                       x, y, ts, params, n, minbits);

    if (exact) {
        hipLaunchKernelGGL(k_pass1, dim3(g1used), dim3(BLK), 0, stream,
                           x, y, ts, pol, params, bwp, n, nb, cap1, per, minbits,
                           gcur, recs1, ovfcur, ovfrecs);
        hipLaunchKernelGGL(k_pass2, dim3(NBAND * CPB), dim3(BLK), 0, stream,
                           recs1, gcur, cap1, cap2, tcur, recs2, ovfcur, ovfrecs);
        hipLaunchKernelGGL(k_accum5, dim3(NT2), dim3(BLK), (size_t)nb * TPX2 * 4, stream,
                           recs2, tcur, nb, cap2, out, part2);
        hipLaunchKernelGGL(k_redsum, dim3(nb), dim3(BLK), 0, stream,
                           part2, nb, sumv, sumsq);
        hipLaunchKernelGGL(k_ovf, dim3(64), dim3(BLK), 0, stream,
                           ovfrecs, ovfcur, nb, out, sumv, sumsq);
    } else if (filter) {
        hipLaunchKernelGGL(k_pass1, dim3(g1used), dim3(BLK), 0, stream,
                           x, y, ts, pol, params, bwp, n, nb, cap1, per, minbits,
                           gcur, recs1, ovfcur, ovfrecs);
        hipLaunchKernelGGL(k_accum2, dim3(NT2), dim3(BLK), (size_t)nb * TPX2 * 4, stream,
                           recs1, gcur, nb, cap1, out, sumv, sumsq);
        hipLaunchKernelGGL(k_ovf, dim3(64), dim3(BLK), 0, stream,
                           ovfrecs, ovfcur, nb, out, sumv, sumsq);
    } else {
        hipLaunchKernelGGL(k_scatter, dim3(2048), dim3(BLK), 0, stream,
                           x, y, ts, pol, params, bwp, n, nb, minbits, out);
        hipLaunchKernelGGL(k_sums, dim3(nb * VAR_SPLIT), dim3(BLK), 0, stream,
                           out, sumv, sumsq);
    }

    hipLaunchKernelGGL(k_final, dim3(1), dim3(BLK), 0, stream,
                       sumv, sumsq, nb, out + n_tensor);
}